// Round 10
// baseline (275.491 us; speedup 1.0000x reference)
//
#include <hip/hip_runtime.h>
#include <hip/hip_bf16.h>
#include <stdint.h>

#define B_   64
#define N_   128
#define H_   256
#define FH   1024   // 4*H
#define NT   32     // trunks
#define TL   32     // trunk len
#define LV   3
#define OUT_ 10

typedef __attribute__((ext_vector_type(4))) int   int4v;
typedef __attribute__((ext_vector_type(4))) float f32x4;

#define QW  (0.0625f / 127.0f)         // weight quant scale
#define QWI (127.0f / 0.0625f)         // 1/QW
#define QH  (1.0f / 127.0f)            // h quant scale
#define QS  (QW * QH)                  // combined dequant for i32 acc
#define L2E 1.442695041f               // log2(e)
#define QSI (-L2E * QS)                // sigmoid-gate dequant (pre-negated+scaled)
#define QSG (2.0f * L2E * QS)          // tanh-gate dequant
#define C2  (2.0f * L2E)               // tanh(c) input scale

__device__ inline float exp2f_(float x) { return __builtin_amdgcn_exp2f(x); }
__device__ inline float rcpf_(float x)  { return __builtin_amdgcn_rcpf(x); }
__device__ inline int clampi_(int a) { return a > 127 ? 127 : (a < -127 ? -127 : a); }
__device__ inline int packq_(float4 f) {
    int a = clampi_(__float2int_rn(f.x * QWI));
    int b = clampi_(__float2int_rn(f.y * QWI));
    int c = clampi_(__float2int_rn(f.z * QWI));
    int d = clampi_(__float2int_rn(f.w * QWI));
    return (a & 255) | ((b & 255) << 8) | ((c & 255) << 16) | ((d & 255) << 24);
}

// Single fused kernel. 192 blocks = 3 levels x 32 trunks x 2 batch-halves.
// 1024 threads = 16 waves = 4 waves/SIMD (vs R9's 2): the issue-bound VALU+trans
// stream now has 2x the wave overlap. Per-wave Breg is only 64 VGPRs (16 gate
// cols), so the body fits the mandatory 128-VGPR budget without forcing games.
// All prep (u/v GEMV, W_hh fp32->int8 quant, bias) is done in-kernel: one dispatch.
__global__ __launch_bounds__(1024)
void lstm_all(const float* __restrict__ bfeat, const int* __restrict__ trunk_idx,
              const int* __restrict__ trunk_len,
              const float* __restrict__ W_enc, const float* __restrict__ b_enc,
              const float* __restrict__ W_ih, const float* __restrict__ b_ih,
              const float* __restrict__ b_hh, const float* __restrict__ W_hh,
              const float* __restrict__ W_lin, const float* __restrict__ b_lin,
              float* __restrict__ out) {
    __shared__ __align__(16) char hbuf[2][32][272];   // int8 h, parity dbuf, 256+16 pad
    __shared__ __align__(16) float sbuf[2][32];       // batch scalars, parity dbuf
    __shared__ __align__(16) float uvU[FH], uvV[FH];  // pre-scaled gate coefficients

    const int bid = blockIdx.x;
    const int l = bid >> 6;
    const int rem = bid & 63;
    const int t = rem >> 1;
    const int b0 = (rem & 1) * 32;

    const int tid = threadIdx.x;
    const int w = tid >> 6;              // wave 0..15 -> gate-col slice [w*16, w*16+16) per gate
    const int lane = tid & 63;
    const int col = lane & 15;
    const int q = lane >> 4;

    // ---- prep A: u/v for this level (redundant across blocks, off critical path)
    // u[j] = s_g * (W_ih[j,:].W_enc) ; v[j] = s_g * (W_ih[j,:].b_enc + b_ih + b_hh)
    {
        const int j = tid;               // 0..1023
        const float4* wr = (const float4*)(W_ih + ((size_t)l * FH + j) * H_);
        const float4* we = (const float4*)W_enc;
        const float4* be = (const float4*)b_enc;
        float du = 0.f, dv = 0.f;
        for (int k2 = 0; k2 < 64; ++k2) {
            float4 a = wr[k2], b = we[k2], c = be[k2];
            du = fmaf(a.x, b.x, fmaf(a.y, b.y, fmaf(a.z, b.z, fmaf(a.w, b.w, du))));
            dv = fmaf(a.x, c.x, fmaf(a.y, c.y, fmaf(a.z, c.z, fmaf(a.w, c.w, dv))));
        }
        int g = j >> 8;
        float s = (g == 2) ? C2 : -L2E;
        uvU[j] = s * du;
        uvV[j] = s * (dv + b_ih[l * FH + j] + b_hh[l * FH + j]);
    }

    // ---- prep B: quantize this wave's W_hh slice fp32 -> int8 B-fragments (64 VGPR)
    int4v Breg[4][4];                    // [g][k]
    #pragma unroll
    for (int g = 0; g < 4; ++g) {
        int j = g * 256 + w * 16 + col;
        const float* bp = W_hh + ((size_t)l * FH + j) * H_ + q * 16;
        #pragma unroll
        for (int k = 0; k < 4; ++k) {
            const float4* fp = (const float4*)(bp + k * 64);
            int4v r;
            r[0] = packq_(fp[0]); r[1] = packq_(fp[1]);
            r[2] = packq_(fp[2]); r[3] = packq_(fp[3]);
            Breg[g][k] = r;
        }
    }

    int len = trunk_len[l * NT + t];
    if (len < 1) len = 1;
    const int* tix = trunk_idx + (l * NT + t) * TL;

    if (tid < 32) sbuf[0][tid] = bfeat[(b0 + tid) * N_ + tix[0]];
    __syncthreads();   // uv + sbuf[0] ready

    float u_r[4], v_r[4];
    #pragma unroll
    for (int g = 0; g < 4; ++g) {
        int j = g * 256 + w * 16 + col;
        u_r[g] = uvU[j];
        v_r[g] = uvV[j];
    }

    float c_r[2][4];                     // [mt][rg]

    // ---- peeled step 0: no h yet (acc = 0) ----
    {
        if (len > 1 && tid < 32) sbuf[1][tid] = bfeat[(b0 + tid) * N_ + tix[1]];
        #pragma unroll
        for (int mt = 0; mt < 2; ++mt) {
            f32x4 sv = *(const f32x4*)&sbuf[0][mt * 16 + q * 4];
            #pragma unroll
            for (int rg = 0; rg < 4; ++rg) {
                float xi = fmaf(sv[rg], u_r[0], v_r[0]);
                float xg = fmaf(sv[rg], u_r[2], v_r[2]);
                float xo = fmaf(sv[rg], u_r[3], v_r[3]);
                float si = rcpf_(exp2f_(xi) + 1.0f);
                float so = rcpf_(exp2f_(xo) + 1.0f);
                float tg = fmaf(-2.0f, rcpf_(exp2f_(xg) + 1.0f), 1.0f);
                float cn = si * tg;                       // c0 = 0
                c_r[mt][rg] = cn;
                float th = fmaf(-2.0f, rcpf_(exp2f_(C2 * cn) + 1.0f), 1.0f);
                hbuf[1][mt * 16 + q * 4 + rg][w * 16 + col] =
                    (char)__float2int_rn(so * th * 127.0f);
            }
        }
        __syncthreads();
    }

    for (int p = 1; p < len; ++p) {
        const int ri = p & 1, wi = ri ^ 1;

        if (p + 1 < len && tid < 32)
            sbuf[wi][tid] = bfeat[(b0 + tid) * N_ + tix[p + 1]];

        #pragma unroll
        for (int mt = 0; mt < 2; ++mt) {
            int4v a_f[4];
            #pragma unroll
            for (int k = 0; k < 4; ++k)
                a_f[k] = *(const int4v*)&hbuf[ri][mt * 16 + col][k * 64 + q * 16];

            f32x4 sv = *(const f32x4*)&sbuf[ri][mt * 16 + q * 4];

            int4v acc[4];
            #pragma unroll
            for (int g = 0; g < 4; ++g)
                #pragma unroll
                for (int rg = 0; rg < 4; ++rg) acc[g][rg] = 0;

            #pragma unroll
            for (int g = 0; g < 4; ++g)
                #pragma unroll
                for (int k = 0; k < 4; ++k)
                    acc[g] = __builtin_amdgcn_mfma_i32_16x16x64_i8(
                        a_f[k], Breg[g][k], acc[g], 0, 0, 0);

            #pragma unroll
            for (int rg = 0; rg < 4; ++rg) {
                float xi = fmaf((float)acc[0][rg], QSI, fmaf(sv[rg], u_r[0], v_r[0]));
                float xf = fmaf((float)acc[1][rg], QSI, fmaf(sv[rg], u_r[1], v_r[1]));
                float xg = fmaf((float)acc[2][rg], QSG, fmaf(sv[rg], u_r[2], v_r[2]));
                float xo = fmaf((float)acc[3][rg], QSI, fmaf(sv[rg], u_r[3], v_r[3]));
                float si = rcpf_(exp2f_(xi) + 1.0f);          // sigmoid
                float sf = rcpf_(exp2f_(xf) + 1.0f);
                float so = rcpf_(exp2f_(xo) + 1.0f);
                float tg = fmaf(-2.0f, rcpf_(exp2f_(xg) + 1.0f), 1.0f);   // tanh
                float cn = fmaf(sf, c_r[mt][rg], si * tg);
                c_r[mt][rg] = cn;
                float th = fmaf(-2.0f, rcpf_(exp2f_(C2 * cn) + 1.0f), 1.0f);
                hbuf[wi][mt * 16 + q * 4 + rg][w * 16 + col] =
                    (char)__float2int_rn(so * th * 127.0f);
            }
        }

        __syncthreads();   // single barrier: new h (wi) + next sbuf ready
    }

    // epilogue: h_last lives in hbuf[len & 1]; bias added by the two t==0 blocks per level
    const char (*hl)[272] = hbuf[len & 1];
    const float* wl = W_lin + l * H_ * OUT_;
    if (tid < 32 * OUT_) {
        int m = tid / OUT_, o = tid % OUT_;
        float s = 0.f;
        for (int k = 0; k < H_; ++k)
            s += (float)hl[m][k] * QH * wl[k * OUT_ + o];
        if (rem < 2) s += b_lin[l * OUT_ + o];
        atomicAdd(&out[(b0 + m) * OUT_ + o], s);
    }
}

extern "C" void kernel_launch(void* const* d_in, const int* in_sizes, int n_in,
                              void* d_out, int out_size, void* d_ws, size_t ws_size,
                              hipStream_t stream) {
    const float* bfeat = (const float*)d_in[0];
    const int*   tidx  = (const int*)d_in[1];
    const int*   tlen  = (const int*)d_in[2];
    const float* W_enc = (const float*)d_in[3];
    const float* b_enc = (const float*)d_in[4];
    const float* W_ih  = (const float*)d_in[5];
    const float* W_hh  = (const float*)d_in[6];
    const float* b_ih  = (const float*)d_in[7];
    const float* b_hh  = (const float*)d_in[8];
    const float* W_lin = (const float*)d_in[9];
    const float* b_lin = (const float*)d_in[10];
    float* out = (float*)d_out;

    hipMemsetAsync(out, 0, (size_t)B_ * OUT_ * sizeof(float), stream);
    lstm_all<<<LV * NT * 2, 1024, 0, stream>>>(bfeat, tidx, tlen, W_enc, b_enc,
                                               W_ih, b_ih, b_hh, W_hh, W_lin, b_lin, out);
}

// Round 11
// 190.531 us; speedup vs baseline: 1.4459x; 1.4459x over previous
//
#include <hip/hip_runtime.h>
#include <hip/hip_bf16.h>
#include <stdint.h>

#define B_   64
#define N_   128
#define H_   256
#define FH   1024   // 4*H
#define NT   32     // trunks
#define TL   32     // trunk len
#define LV   3
#define OUT_ 10

typedef __attribute__((ext_vector_type(4))) int   int4v;
typedef __attribute__((ext_vector_type(4))) float f32x4;

#define QW  (0.0625f / 127.0f)         // weight quant scale
#define QH  (1.0f / 127.0f)            // h quant scale
#define QS  (QW * QH)                  // combined dequant for i32 acc
#define L2E 1.442695041f               // log2(e)
#define QSI (-L2E * QS)                // sigmoid-gate dequant (pre-negated+scaled)
#define QSG (2.0f * L2E * QS)          // tanh-gate dequant
#define C2  (2.0f * L2E)               // tanh(c) input scale

__device__ inline float exp2f_(float x) { return __builtin_amdgcn_exp2f(x); }
__device__ inline float rcpf_(float x)  { return __builtin_amdgcn_rcpf(x); }

// merged prep (R8's — measured cheap). blocks 0..767: u/v (4 j per block, one
// per wave). blocks 768..1535: W_hh->int8 + out init with summed bias.
__global__ void prep_all(const float* __restrict__ W_enc, const float* __restrict__ b_enc,
                         const float* __restrict__ W_ih, const float* __restrict__ b_ih,
                         const float* __restrict__ b_hh, const float* __restrict__ W_hh,
                         const float* __restrict__ b_lin,
                         float* __restrict__ u, float* __restrict__ v,
                         char* __restrict__ whh_i8, float* __restrict__ out) {
    int blk = blockIdx.x;
    int tid = threadIdx.x;
    if (blk < 768) {
        int j = blk * 4 + (tid >> 6);   // 0..3071
        int lane = tid & 63;
        const float4 w  = ((const float4*)(W_ih + (size_t)j * H_))[lane];
        const float4 we = ((const float4*)W_enc)[lane];
        const float4 be = ((const float4*)b_enc)[lane];
        float du = w.x * we.x + w.y * we.y + w.z * we.z + w.w * we.w;
        float dv = w.x * be.x + w.y * be.y + w.z * be.z + w.w * be.w;
        for (int m = 32; m >= 1; m >>= 1) { du += __shfl_xor(du, m); dv += __shfl_xor(dv, m); }
        if (lane == 0) {
            int g = (j & 1023) >> 8;
            float s = (g == 2) ? (2.0f * L2E) : (-L2E);
            u[j] = s * du;
            v[j] = s * (dv + b_ih[j] + b_hh[j]);
        }
    } else {
        int gid = (blk - 768) * 256 + tid;   // 0..196607, each converts 4
        const float4 w = ((const float4*)W_hh)[gid];
        char4 o;
        int a0 = __float2int_rn(w.x * (127.0f / 0.0625f));
        int a1 = __float2int_rn(w.y * (127.0f / 0.0625f));
        int a2 = __float2int_rn(w.z * (127.0f / 0.0625f));
        int a3 = __float2int_rn(w.w * (127.0f / 0.0625f));
        a0 = a0 > 127 ? 127 : (a0 < -127 ? -127 : a0);
        a1 = a1 > 127 ? 127 : (a1 < -127 ? -127 : a1);
        a2 = a2 > 127 ? 127 : (a2 < -127 ? -127 : a2);
        a3 = a3 > 127 ? 127 : (a3 < -127 ? -127 : a3);
        o.x = (char)a0; o.y = (char)a1; o.z = (char)a2; o.w = (char)a3;
        ((char4*)whh_i8)[gid] = o;
        if (gid < B_ * OUT_) {
            int oo = gid % OUT_;
            out[gid] = b_lin[oo] + b_lin[OUT_ + oo] + b_lin[2 * OUT_ + oo];
        }
    }
}

// Main: 192 independent blocks = 3 levels x 32 trunks x 2 batch-halves.
// 1024 threads = 16 waves = 4 waves/SIMD for issue-slot filling (R9 ran 61%
// normalized VALUBusy at 2 waves/SIMD). waves_per_eu(4,4) caps occupancy at
// exactly 4/EU -> 128-VGPR budget, preventing R10's silent 8/EU + spill
// (VGPR=64, 120 MB scratch writes). Per-wave: 16 h-cols x 4 gates,
// Breg[4][4] = 64 VGPR. M=32 rows. One barrier/step, parity dbuf hbuf,
// svals prefetch, peeled step 0.
__global__ __launch_bounds__(1024) __attribute__((amdgpu_waves_per_eu(4, 4)))
void lstm_main(const float* __restrict__ bfeat, const int* __restrict__ trunk_idx,
               const int* __restrict__ trunk_len,
               const char* __restrict__ whh_i8,
               const float* __restrict__ u, const float* __restrict__ v,
               const float* __restrict__ W_lin, float* __restrict__ out) {
    __shared__ __align__(16) char hbuf[2][32][272];   // int8 h, parity dbuf, 256+16 pad
    __shared__ __align__(16) float sbuf[2][32];       // batch scalars, parity dbuf

    const int bid = blockIdx.x;
    const int l = bid >> 6;
    const int rem = bid & 63;
    const int t = rem >> 1;
    const int b0 = (rem & 1) * 32;

    const int tid = threadIdx.x;
    const int w = tid >> 6;              // wave 0..15 -> h-cols [w*16, w*16+16) per gate
    const int lane = tid & 63;
    const int col = lane & 15;
    const int q = lane >> 4;

    const char* whh_l = whh_i8 + (size_t)l * FH * H_;

    // W_hh slice -> registers/stream (64 VGPR). Wave w owns gate cols
    // j = g*256 + w*16 + col, g = 0..3.
    int4v Breg[4][4];                    // [g][k]
    #pragma unroll
    for (int g = 0; g < 4; ++g) {
        int j = g * 256 + w * 16 + col;
        const char* bp = whh_l + (size_t)j * H_ + q * 16;
        #pragma unroll
        for (int k = 0; k < 4; ++k)
            Breg[g][k] = *(const int4v*)(bp + k * 64);
    }

    float u_r[4], v_r[4];                // pre-scaled by prep
    {
        const float* u_l = u + l * FH;
        const float* v_l = v + l * FH;
        #pragma unroll
        for (int g = 0; g < 4; ++g) {
            int j = g * 256 + w * 16 + col;
            u_r[g] = u_l[j];
            v_r[g] = v_l[j];
        }
    }

    float c_r[2][4];                     // [mt][rg]

    int len = trunk_len[l * NT + t];
    if (len < 1) len = 1;
    const int* tix = trunk_idx + (l * NT + t) * TL;

    // prologue: svals for step 0
    if (tid < 32) sbuf[0][tid] = bfeat[(b0 + tid) * N_ + tix[0]];
    __syncthreads();

    // ---- peeled step 0: no h yet (acc = 0) ----
    {
        if (len > 1 && tid < 32) sbuf[1][tid] = bfeat[(b0 + tid) * N_ + tix[1]];
        #pragma unroll
        for (int mt = 0; mt < 2; ++mt) {
            f32x4 sv = *(const f32x4*)&sbuf[0][mt * 16 + q * 4];
            #pragma unroll
            for (int rg = 0; rg < 4; ++rg) {
                float xi = fmaf(sv[rg], u_r[0], v_r[0]);
                float xg = fmaf(sv[rg], u_r[2], v_r[2]);
                float xo = fmaf(sv[rg], u_r[3], v_r[3]);
                float si = rcpf_(exp2f_(xi) + 1.0f);
                float so = rcpf_(exp2f_(xo) + 1.0f);
                float tg = fmaf(-2.0f, rcpf_(exp2f_(xg) + 1.0f), 1.0f);
                float cn = si * tg;                       // c0 = 0
                c_r[mt][rg] = cn;
                float th = fmaf(-2.0f, rcpf_(exp2f_(C2 * cn) + 1.0f), 1.0f);
                hbuf[1][mt * 16 + q * 4 + rg][w * 16 + col] =
                    (char)__float2int_rn(so * th * 127.0f);
            }
        }
        __syncthreads();
    }

    for (int p = 1; p < len; ++p) {
        const int ri = p & 1, wi = ri ^ 1;

        if (p + 1 < len && tid < 32)
            sbuf[wi][tid] = bfeat[(b0 + tid) * N_ + tix[p + 1]];

        #pragma unroll
        for (int mt = 0; mt < 2; ++mt) {
            int4v a_f[4];
            #pragma unroll
            for (int k = 0; k < 4; ++k)
                a_f[k] = *(const int4v*)&hbuf[ri][mt * 16 + col][k * 64 + q * 16];

            f32x4 sv = *(const f32x4*)&sbuf[ri][mt * 16 + q * 4];

            int4v acc[4];
            #pragma unroll
            for (int g = 0; g < 4; ++g)
                #pragma unroll
                for (int rg = 0; rg < 4; ++rg) acc[g][rg] = 0;

            #pragma unroll
            for (int g = 0; g < 4; ++g)
                #pragma unroll
                for (int k = 0; k < 4; ++k)
                    acc[g] = __builtin_amdgcn_mfma_i32_16x16x64_i8(
                        a_f[k], Breg[g][k], acc[g], 0, 0, 0);

            #pragma unroll
            for (int rg = 0; rg < 4; ++rg) {
                float xi = fmaf((float)acc[0][rg], QSI, fmaf(sv[rg], u_r[0], v_r[0]));
                float xf = fmaf((float)acc[1][rg], QSI, fmaf(sv[rg], u_r[1], v_r[1]));
                float xg = fmaf((float)acc[2][rg], QSG, fmaf(sv[rg], u_r[2], v_r[2]));
                float xo = fmaf((float)acc[3][rg], QSI, fmaf(sv[rg], u_r[3], v_r[3]));
                float si = rcpf_(exp2f_(xi) + 1.0f);          // sigmoid
                float sf = rcpf_(exp2f_(xf) + 1.0f);
                float so = rcpf_(exp2f_(xo) + 1.0f);
                float tg = fmaf(-2.0f, rcpf_(exp2f_(xg) + 1.0f), 1.0f);   // tanh
                float cn = fmaf(sf, c_r[mt][rg], si * tg);
                c_r[mt][rg] = cn;
                float th = fmaf(-2.0f, rcpf_(exp2f_(C2 * cn) + 1.0f), 1.0f);
                hbuf[wi][mt * 16 + q * 4 + rg][w * 16 + col] =
                    (char)__float2int_rn(so * th * 127.0f);
            }
        }

        __syncthreads();   // single barrier: new h (wi) + next sbuf ready
    }

    // epilogue: h_last lives in hbuf[len & 1]; bias pre-initialized in out by prep
    const char (*hl)[272] = hbuf[len & 1];
    const float* wl = W_lin + l * H_ * OUT_;
    if (tid < 32 * OUT_) {
        int m = tid / OUT_, o = tid % OUT_;
        float s = 0.f;
        for (int k = 0; k < H_; ++k)
            s += (float)hl[m][k] * QH * wl[k * OUT_ + o];
        atomicAdd(&out[(b0 + m) * OUT_ + o], s);
    }
}

extern "C" void kernel_launch(void* const* d_in, const int* in_sizes, int n_in,
                              void* d_out, int out_size, void* d_ws, size_t ws_size,
                              hipStream_t stream) {
    const float* bfeat = (const float*)d_in[0];
    const int*   tidx  = (const int*)d_in[1];
    const int*   tlen  = (const int*)d_in[2];
    const float* W_enc = (const float*)d_in[3];
    const float* b_enc = (const float*)d_in[4];
    const float* W_ih  = (const float*)d_in[5];
    const float* W_hh  = (const float*)d_in[6];
    const float* b_ih  = (const float*)d_in[7];
    const float* b_hh  = (const float*)d_in[8];
    const float* W_lin = (const float*)d_in[9];
    const float* b_lin = (const float*)d_in[10];
    float* out = (float*)d_out;

    char* whh_i8 = (char*)d_ws;                                // 786,432 B
    float* u = (float*)((char*)d_ws + 786432);                 // 12,288 B
    float* v = (float*)((char*)d_ws + 786432 + 12288);         // 12,288 B

    prep_all<<<1536, 256, 0, stream>>>(W_enc, b_enc, W_ih, b_ih, b_hh, W_hh, b_lin,
                                       u, v, whh_i8, out);
    lstm_main<<<LV * NT * 2, 1024, 0, stream>>>(bfeat, tidx, tlen, whh_i8, u, v, W_lin, out);
}